// Round 2
// baseline (767.504 us; speedup 1.0000x reference)
//
#include <hip/hip_runtime.h>
#include <hip/hip_bf16.h>
#include <type_traits>

// STPT-Light: x->(Q,K,V) proj, L2-norm K, scalar-decay linear-attn scan, out proj.
// B=4 T=1024 D=1024 H=16 DK=64.
// DTYPE-ROBUST: detector kernel decides f32 vs bf16 wire format at runtime;
// inputs canonicalized to bf16 in ws, intermediates f32, output store branches.
//
// ws layout (bytes):
//   0      x_b    8MB      (4096x1024 bf16)
//   8MB    Wq_b   2MB      10MB Wk_b  12MB Wv_b  14MB Wo_b
//   16MB   Qf     16MB     (4096x1024 f32)
//   32MB   Kf     16MB
//   48MB   Vf     16MB
//   64MB   rho    256KB    (64 x 1024 f32)
//   65MB   Yb     8MB      (4096x1024 bf16)
//   73MB   pf     256B     (4x16 f32 params)
//   73MB+1KB flag 4B
// total ~73.1MB

typedef __bf16 b16x8 __attribute__((ext_vector_type(8)));
typedef float  f32x4 __attribute__((ext_vector_type(4)));
typedef unsigned short u16x8 __attribute__((ext_vector_type(8)));
using bf16_t = __hip_bfloat16;

#define AS1C(p) ((const __attribute__((address_space(1))) void*)(p))
#define AS3(p)  ((__attribute__((address_space(3))) void*)(p))

__device__ __forceinline__ void g2l16(const void* g, void* l) {
  __builtin_amdgcn_global_load_lds(AS1C(g), AS3(l), 16, 0, 0);
}
__device__ __forceinline__ void g2l4(const void* g, void* l) {
  __builtin_amdgcn_global_load_lds(AS1C(g), AS3(l), 4, 0, 0);
}

__device__ __forceinline__ unsigned short f2b(float x) {  // RNE f32->bf16 bits
  unsigned u = __float_as_uint(x);
  return (unsigned short)((u + 0x7FFFu + ((u >> 16) & 1u)) >> 16);
}
__device__ __forceinline__ float b2f(unsigned short b) {
  return __uint_as_float(((unsigned)b) << 16);
}

// ---------------------------------------------------------------------------
// Detect wire dtype: genuine f32 N(0,1) has exponent field in [95,135];
// bf16-pairs reinterpreted as f32 land at wild exponents. One wave.
// ---------------------------------------------------------------------------
__global__ void detect_dtype(const unsigned* __restrict__ x, int* __restrict__ flag) {
  unsigned u = x[threadIdx.x];
  int e = (int)((u >> 23) & 0xFF);
  int ok = (e >= 95 && e <= 135);
  unsigned long long m = __ballot(ok);
  if (threadIdx.x == 0) *flag = (__popcll(m) >= 32) ? 1 : 0;  // 1 = f32 wire
}

// ---------------------------------------------------------------------------
// Canonicalize an input tensor to bf16. n multiple of 8.
// ---------------------------------------------------------------------------
__global__ __launch_bounds__(256)
void convert_bf16(const void* __restrict__ src, bf16_t* __restrict__ dst, int n,
                  const int* __restrict__ flag) {
  const int f = *flag;
  const int i = (blockIdx.x * 256 + threadIdx.x) * 8;
  if (i >= n) return;
  if (f) {
    const float4 a = *(const float4*)((const float*)src + i);
    const float4 b = *(const float4*)((const float*)src + i + 4);
    u16x8 o;
    o[0] = f2b(a.x); o[1] = f2b(a.y); o[2] = f2b(a.z); o[3] = f2b(a.w);
    o[4] = f2b(b.x); o[5] = f2b(b.y); o[6] = f2b(b.z); o[7] = f2b(b.w);
    *(u16x8*)((unsigned short*)dst + i) = o;
  } else {
    *(int4*)((unsigned short*)dst + i) = *(const int4*)((const unsigned short*)src + i);
  }
}

__global__ void conv_params(const void* g, const void* bgp, const void* l, const void* blp,
                            float* __restrict__ pf, const int* __restrict__ flag) {
  const int t = threadIdx.x;
  const void* s = (t < 16) ? g : (t < 32) ? bgp : (t < 48) ? l : blp;
  const int h = t & 15;
  float v;
  if (*flag) v = ((const float*)s)[h];
  else       v = b2f(((const unsigned short*)s)[h]);
  pf[t] = v;
}

// ---------------------------------------------------------------------------
// C[m,n] = sum_k A[m,k]*B[n,k]. 128x128 tile, BK=32, 4 waves, m97 structure.
// OutT float -> f32 store; FLAGOUT -> runtime-flagged f32/bf16 store into void*.
// ---------------------------------------------------------------------------
template <bool FLAGOUT, typename OutT>
__global__ __launch_bounds__(256)
void gemm_bt(const bf16_t* __restrict__ A, const bf16_t* __restrict__ B,
             void* __restrict__ C, int M, int N, int K, const int* __restrict__ flag)
{
  __shared__ __align__(16) unsigned short As[128 * 32];
  __shared__ __align__(16) unsigned short Bs[128 * 32];
  const int tid  = threadIdx.x;
  const int lane = tid & 63;
  const int wave = tid >> 6;
  const int wm = wave >> 1, wn = wave & 1;
  const int quad = lane >> 4, tm = lane & 15;
  const long row0 = (long)blockIdx.y * 128;
  const long col0 = (long)blockIdx.x * 128;

  f32x4 acc[4][4];
#pragma unroll
  for (int i = 0; i < 4; ++i)
#pragma unroll
    for (int j = 0; j < 4; ++j) acc[i][j] = (f32x4){0.f, 0.f, 0.f, 0.f};

  const int sr = tid >> 2;
  const int sc = (tid & 3) * 8;
  const bf16_t* ap = A + (row0 + sr) * (long)K + sc;
  const bf16_t* bp = B + (col0 + sr) * (long)K + sc;
  unsigned short* la = As + tid * 8;
  unsigned short* lb = Bs + tid * 8;

  for (int kt = 0; kt < K; kt += 32) {
    __syncthreads();
    g2l16(ap + kt,           la);
    g2l16(ap + 64l * K + kt, la + 2048);
    g2l16(bp + kt,           lb);
    g2l16(bp + 64l * K + kt, lb + 2048);
    __syncthreads();

    b16x8 af[4], bfr[4];
#pragma unroll
    for (int i = 0; i < 4; ++i)
      af[i] = *(const b16x8*)&As[(wm * 64 + i * 16 + tm) * 32 + quad * 8];
#pragma unroll
    for (int j = 0; j < 4; ++j)
      bfr[j] = *(const b16x8*)&Bs[(wn * 64 + j * 16 + tm) * 32 + quad * 8];
#pragma unroll
    for (int i = 0; i < 4; ++i)
#pragma unroll
      for (int j = 0; j < 4; ++j)
        acc[i][j] = __builtin_amdgcn_mfma_f32_16x16x32_bf16(af[i], bfr[j], acc[i][j], 0, 0, 0);
  }

  const int fm = FLAGOUT ? *flag : 0;
  // C/D layout (m89-verified): col = lane&15, row = (lane>>4)*4 + reg
#pragma unroll
  for (int i = 0; i < 4; ++i)
#pragma unroll
    for (int j = 0; j < 4; ++j)
#pragma unroll
      for (int r = 0; r < 4; ++r) {
        long row = row0 + wm * 64 + i * 16 + quad * 4 + r;
        long col = col0 + wn * 64 + j * 16 + tm;
        float v = acc[i][j][r];
        if constexpr (FLAGOUT) {
          if (fm) ((float*)C)[row * N + col] = v;
          else    ((unsigned short*)C)[row * N + col] = f2b(v);
        } else {
          ((OutT*)C)[row * N + col] = v;
        }
      }
}

// ---------------------------------------------------------------------------
// Normalize K rows (per (n,h): 64-elem L2 norm) in place; compute rho[bh,t].
// One wave per (n,h). pf = [Wg(16) bg(16) Wl(16) bl(16)] f32.
// ---------------------------------------------------------------------------
__global__ __launch_bounds__(256)
void norm_rho(float* __restrict__ K, float* __restrict__ rho,
              const float* __restrict__ pf)
{
  const int g    = blockIdx.x * 4 + (threadIdx.x >> 6);
  const int lane = threadIdx.x & 63;
  const int n = g >> 4, h = g & 15;
  const size_t idx = (size_t)n * 1024 + h * 64 + lane;
  float kv = K[idx];
  float ss = kv * kv;
#pragma unroll
  for (int m = 1; m < 64; m <<= 1) ss += __shfl_xor(ss, m);
  float kn = kv / fmaxf(sqrtf(ss), 1e-12f);
  K[idx] = kn;
  float s = kn;
#pragma unroll
  for (int m = 1; m < 64; m <<= 1) s += __shfl_xor(s, m);
  if (lane == 0) {
    float kbar = s * (1.f / 64.f);
    float gm = 1.f / (1.f + expf(-(pf[h]      * kbar + pf[16 + h])));
    float lm = 1.f / (1.f + expf(-(pf[32 + h] * kbar + pf[48 + h])));
    const int b = n >> 10, t = n & 1023;   // T = 1024
    rho[(size_t)(b * 16 + h) * 1024 + t] = (1.f - lm) * gm;
  }
}

// ---------------------------------------------------------------------------
// Sequential scan: one wave per (b,h). Lane owns S[:,kc] (64 VGPRs).
// ---------------------------------------------------------------------------
__global__ __launch_bounds__(64)
void scan_bh(const float* __restrict__ Q, const float* __restrict__ Kn,
             const float* __restrict__ V, const float* __restrict__ rho,
             bf16_t* __restrict__ Y)
{
  __shared__ __align__(16) float q_s[64 * 64];
  __shared__ __align__(16) float k_s[64 * 64];
  __shared__ __align__(16) float v_s[64 * 64];
  __shared__ __align__(16) float rho_s[64];
  const int bh = blockIdx.x;
  const int b = bh >> 4, h = bh & 15;
  const int lane = threadIdx.x;          // kc = lane
  const long n0 = (long)b * 1024;        // b*T

  float S[64];
#pragma unroll
  for (int i = 0; i < 64; ++i) S[i] = 0.f;

  const int trow = lane >> 4;            // 0..3
  const int tcol = (lane & 15) * 4;      // float offset

  for (int tc = 0; tc < 16; ++tc) {
    __syncthreads();
#pragma unroll 4
    for (int it = 0; it < 16; ++it) {
      const long t = (long)tc * 64 + it * 4 + trow;
      const long goff = (n0 + t) * 1024 + h * 64 + tcol;
      g2l16(Q  + goff, q_s + it * 256 + lane * 4);
      g2l16(Kn + goff, k_s + it * 256 + lane * 4);
      g2l16(V  + goff, v_s + it * 256 + lane * 4);
    }
    g2l4(rho + (size_t)bh * 1024 + tc * 64 + lane, rho_s + lane);
    __builtin_amdgcn_s_waitcnt(0);
    __syncthreads();

    for (int it = 0; it < 64; ++it) {
      const float r = rho_s[it];
      const float coef = (1.f - r) * k_s[it * 64 + lane];
      const float* vp = v_s + it * 64;
      const float* qp = q_s + it * 64;
      float y0 = 0.f, y1 = 0.f, y2 = 0.f, y3 = 0.f;
#pragma unroll
      for (int v4 = 0; v4 < 16; ++v4) {
        const float4 vv = *(const float4*)(vp + v4 * 4);
        const float4 qq = *(const float4*)(qp + v4 * 4);
        float s0 = r * S[v4 * 4 + 0] + coef * vv.x; S[v4 * 4 + 0] = s0; y0 += qq.x * s0;
        float s1 = r * S[v4 * 4 + 1] + coef * vv.y; S[v4 * 4 + 1] = s1; y1 += qq.y * s1;
        float s2 = r * S[v4 * 4 + 2] + coef * vv.z; S[v4 * 4 + 2] = s2; y2 += qq.z * s2;
        float s3 = r * S[v4 * 4 + 3] + coef * vv.w; S[v4 * 4 + 3] = s3; y3 += qq.w * s3;
      }
      const long t = (long)tc * 64 + it;
      Y[(n0 + t) * 1024 + h * 64 + lane] = __float2bfloat16((y0 + y1) + (y2 + y3));
    }
  }
}

// ---------------------------------------------------------------------------
extern "C" void kernel_launch(void* const* d_in, const int* in_sizes, int n_in,
                              void* d_out, int out_size, void* d_ws, size_t ws_size,
                              hipStream_t stream) {
  const void* x  = d_in[0];
  const void* Wq = d_in[1];
  const void* Wk = d_in[2];
  const void* Wv = d_in[3];
  const void* Wo = d_in[4];

  char* ws = (char*)d_ws;
  const size_t MB = 1ull << 20;
  bf16_t* x_b  = (bf16_t*)(ws);
  bf16_t* Wq_b = (bf16_t*)(ws + 8 * MB);
  bf16_t* Wk_b = (bf16_t*)(ws + 10 * MB);
  bf16_t* Wv_b = (bf16_t*)(ws + 12 * MB);
  bf16_t* Wo_b = (bf16_t*)(ws + 14 * MB);
  float*  Qf   = (float*)(ws + 16 * MB);
  float*  Kf   = (float*)(ws + 32 * MB);
  float*  Vf   = (float*)(ws + 48 * MB);
  float*  rh   = (float*)(ws + 64 * MB);
  bf16_t* Yb   = (bf16_t*)(ws + 65 * MB);
  float*  pf   = (float*)(ws + 73 * MB);
  int*    flag = (int*)(ws + 73 * MB + 1024);

  detect_dtype<<<1, 64, 0, stream>>>((const unsigned*)x, flag);

  convert_bf16<<<2048, 256, 0, stream>>>(x,  x_b,  4096 * 1024, flag);
  convert_bf16<<<512,  256, 0, stream>>>(Wq, Wq_b, 1024 * 1024, flag);
  convert_bf16<<<512,  256, 0, stream>>>(Wk, Wk_b, 1024 * 1024, flag);
  convert_bf16<<<512,  256, 0, stream>>>(Wv, Wv_b, 1024 * 1024, flag);
  convert_bf16<<<512,  256, 0, stream>>>(Wo, Wo_b, 1024 * 1024, flag);
  conv_params<<<1, 64, 0, stream>>>(d_in[5], d_in[6], d_in[7], d_in[8], pf, flag);

  dim3 blk(256), gg(8, 32, 1);
  gemm_bt<false, float><<<gg, blk, 0, stream>>>(x_b, Wq_b, Qf, 4096, 1024, 1024, nullptr);
  gemm_bt<false, float><<<gg, blk, 0, stream>>>(x_b, Wk_b, Kf, 4096, 1024, 1024, nullptr);
  gemm_bt<false, float><<<gg, blk, 0, stream>>>(x_b, Wv_b, Vf, 4096, 1024, 1024, nullptr);
  norm_rho<<<dim3(16384), blk, 0, stream>>>(Kf, rh, pf);
  scan_bh<<<dim3(64), dim3(64), 0, stream>>>(Qf, Kf, Vf, rh, Yb);
  gemm_bt<true, float><<<gg, blk, 0, stream>>>(Yb, Wo_b, d_out, 4096, 1024, 1024, flag);
}

// Round 3
// 214.508 us; speedup vs baseline: 3.5780x; 3.5780x over previous
//
#include <hip/hip_runtime.h>
#include <hip/hip_bf16.h>
#include <type_traits>

// STPT-Light: x->(Q,K,V) proj, L2-norm K, chunked linear-attn scan (MFMA), out proj.
// B=4 T=1024 D=1024 H=16 DK=64. Chunk C=64, 16 chunks, 64 (b,h) pairs.
//
// ws layout (MB): 0 x_b[8] | 8 Wq_b[2] 10 Wk_b[2] 12 Wv_b[2] 14 Wo_b[2]
//   16 Qb[8] 24 Kb[8] 32 Vb[8] 40 Yb[8]  (bf16 4096x1024)
//   48 U[16] (f32 64bh x 16c x 64 x 64)
//   64 Sprev[8] (bf16 64bh x 16c x 64 x 64)
//   72 rho[256KB f32] | 72+256KB A_g[4KB] | 73 pf[256B] | 73+1KB flag[4B]

typedef __bf16 b16x8 __attribute__((ext_vector_type(8)));
typedef float  f32x4 __attribute__((ext_vector_type(4)));
typedef unsigned short u16x8 __attribute__((ext_vector_type(8)));
using bf16_t = __hip_bfloat16;

#define AS1C(p) ((const __attribute__((address_space(1))) void*)(p))
#define AS3(p)  ((__attribute__((address_space(3))) void*)(p))

__device__ __forceinline__ void g2l16(const void* g, void* l) {
  __builtin_amdgcn_global_load_lds(AS1C(g), AS3(l), 16, 0, 0);
}
__device__ __forceinline__ void g2l4(const void* g, void* l) {
  __builtin_amdgcn_global_load_lds(AS1C(g), AS3(l), 4, 0, 0);
}

__device__ __forceinline__ unsigned short f2b(float x) {  // RNE f32->bf16 bits
  unsigned u = __float_as_uint(x);
  return (unsigned short)((u + 0x7FFFu + ((u >> 16) & 1u)) >> 16);
}
__device__ __forceinline__ float b2f(unsigned short b) {
  return __uint_as_float(((unsigned)b) << 16);
}

// ---------------------------------------------------------------------------
__global__ void detect_dtype(const unsigned* __restrict__ x, int* __restrict__ flag) {
  unsigned u = x[threadIdx.x];
  int e = (int)((u >> 23) & 0xFF);
  int ok = (e >= 95 && e <= 135);
  unsigned long long m = __ballot(ok);
  if (threadIdx.x == 0) *flag = (__popcll(m) >= 32) ? 1 : 0;  // 1 = f32 wire
}

__global__ __launch_bounds__(256)
void convert_bf16(const void* __restrict__ src, bf16_t* __restrict__ dst, int n,
                  const int* __restrict__ flag) {
  const int f = *flag;
  const int i = (blockIdx.x * 256 + threadIdx.x) * 8;
  if (i >= n) return;
  if (f) {
    const float4 a = *(const float4*)((const float*)src + i);
    const float4 b = *(const float4*)((const float*)src + i + 4);
    u16x8 o;
    o[0] = f2b(a.x); o[1] = f2b(a.y); o[2] = f2b(a.z); o[3] = f2b(a.w);
    o[4] = f2b(b.x); o[5] = f2b(b.y); o[6] = f2b(b.z); o[7] = f2b(b.w);
    *(u16x8*)((unsigned short*)dst + i) = o;
  } else {
    *(int4*)((unsigned short*)dst + i) = *(const int4*)((const unsigned short*)src + i);
  }
}

__global__ void conv_params(const void* g, const void* bgp, const void* l, const void* blp,
                            float* __restrict__ pf, const int* __restrict__ flag) {
  const int t = threadIdx.x;
  const void* s = (t < 16) ? g : (t < 32) ? bgp : (t < 48) ? l : blp;
  const int h = t & 15;
  float v;
  if (*flag) v = ((const float*)s)[h];
  else       v = b2f(((const unsigned short*)s)[h]);
  pf[t] = v;
}

// ---------------------------------------------------------------------------
// Fused Q/K/V projection: z selects weight/output. C[m,n]=sum_k A[m,k]B[n,k].
// 128x128 tile, BK=32, m97 structure, bf16 out.
// ---------------------------------------------------------------------------
__global__ __launch_bounds__(256)
void gemm_qkv(const bf16_t* __restrict__ A,
              const bf16_t* __restrict__ B0, const bf16_t* __restrict__ B1,
              const bf16_t* __restrict__ B2,
              bf16_t* __restrict__ C0, bf16_t* __restrict__ C1, bf16_t* __restrict__ C2,
              int M, int N, int K)
{
  const bf16_t* B = (blockIdx.z == 0) ? B0 : (blockIdx.z == 1) ? B1 : B2;
  bf16_t*       C = (blockIdx.z == 0) ? C0 : (blockIdx.z == 1) ? C1 : C2;
  __shared__ __align__(16) unsigned short As[128 * 32];
  __shared__ __align__(16) unsigned short Bs[128 * 32];
  const int tid  = threadIdx.x;
  const int lane = tid & 63;
  const int wave = tid >> 6;
  const int wm = wave >> 1, wn = wave & 1;
  const int quad = lane >> 4, tm = lane & 15;
  const long row0 = (long)blockIdx.y * 128;
  const long col0 = (long)blockIdx.x * 128;

  f32x4 acc[4][4];
#pragma unroll
  for (int i = 0; i < 4; ++i)
#pragma unroll
    for (int j = 0; j < 4; ++j) acc[i][j] = (f32x4){0.f, 0.f, 0.f, 0.f};

  const int sr = tid >> 2;
  const int sc = (tid & 3) * 8;
  const bf16_t* ap = A + (row0 + sr) * (long)K + sc;
  const bf16_t* bp = B + (col0 + sr) * (long)K + sc;
  unsigned short* la = As + tid * 8;
  unsigned short* lb = Bs + tid * 8;

  for (int kt = 0; kt < K; kt += 32) {
    __syncthreads();
    g2l16(ap + kt,           la);
    g2l16(ap + 64l * K + kt, la + 2048);
    g2l16(bp + kt,           lb);
    g2l16(bp + 64l * K + kt, lb + 2048);
    __syncthreads();

    b16x8 af[4], bfr[4];
#pragma unroll
    for (int i = 0; i < 4; ++i)
      af[i] = *(const b16x8*)&As[(wm * 64 + i * 16 + tm) * 32 + quad * 8];
#pragma unroll
    for (int j = 0; j < 4; ++j)
      bfr[j] = *(const b16x8*)&Bs[(wn * 64 + j * 16 + tm) * 32 + quad * 8];
#pragma unroll
    for (int i = 0; i < 4; ++i)
#pragma unroll
      for (int j = 0; j < 4; ++j)
        acc[i][j] = __builtin_amdgcn_mfma_f32_16x16x32_bf16(af[i], bfr[j], acc[i][j], 0, 0, 0);
  }

#pragma unroll
  for (int i = 0; i < 4; ++i)
#pragma unroll
    for (int j = 0; j < 4; ++j)
#pragma unroll
      for (int r = 0; r < 4; ++r) {
        long row = row0 + wm * 64 + i * 16 + quad * 4 + r;
        long col = col0 + wn * 64 + j * 16 + tm;
        ((unsigned short*)C)[row * N + col] = f2b(acc[i][j][r]);
      }
}

// ---------------------------------------------------------------------------
// Final GEMM with runtime-flagged f32/bf16 output store.
// ---------------------------------------------------------------------------
__global__ __launch_bounds__(256)
void gemm_out(const bf16_t* __restrict__ A, const bf16_t* __restrict__ B,
              void* __restrict__ C, int M, int N, int K, const int* __restrict__ flag)
{
  __shared__ __align__(16) unsigned short As[128 * 32];
  __shared__ __align__(16) unsigned short Bs[128 * 32];
  const int tid  = threadIdx.x;
  const int lane = tid & 63;
  const int wave = tid >> 6;
  const int wm = wave >> 1, wn = wave & 1;
  const int quad = lane >> 4, tm = lane & 15;
  const long row0 = (long)blockIdx.y * 128;
  const long col0 = (long)blockIdx.x * 128;

  f32x4 acc[4][4];
#pragma unroll
  for (int i = 0; i < 4; ++i)
#pragma unroll
    for (int j = 0; j < 4; ++j) acc[i][j] = (f32x4){0.f, 0.f, 0.f, 0.f};

  const int sr = tid >> 2;
  const int sc = (tid & 3) * 8;
  const bf16_t* ap = A + (row0 + sr) * (long)K + sc;
  const bf16_t* bp = B + (col0 + sr) * (long)K + sc;
  unsigned short* la = As + tid * 8;
  unsigned short* lb = Bs + tid * 8;

  for (int kt = 0; kt < K; kt += 32) {
    __syncthreads();
    g2l16(ap + kt,           la);
    g2l16(ap + 64l * K + kt, la + 2048);
    g2l16(bp + kt,           lb);
    g2l16(bp + 64l * K + kt, lb + 2048);
    __syncthreads();

    b16x8 af[4], bfr[4];
#pragma unroll
    for (int i = 0; i < 4; ++i)
      af[i] = *(const b16x8*)&As[(wm * 64 + i * 16 + tm) * 32 + quad * 8];
#pragma unroll
    for (int j = 0; j < 4; ++j)
      bfr[j] = *(const b16x8*)&Bs[(wn * 64 + j * 16 + tm) * 32 + quad * 8];
#pragma unroll
    for (int i = 0; i < 4; ++i)
#pragma unroll
      for (int j = 0; j < 4; ++j)
        acc[i][j] = __builtin_amdgcn_mfma_f32_16x16x32_bf16(af[i], bfr[j], acc[i][j], 0, 0, 0);
  }

  const int fm = *flag;
#pragma unroll
  for (int i = 0; i < 4; ++i)
#pragma unroll
    for (int j = 0; j < 4; ++j)
#pragma unroll
      for (int r = 0; r < 4; ++r) {
        long row = row0 + wm * 64 + i * 16 + quad * 4 + r;
        long col = col0 + wn * 64 + j * 16 + tm;
        float v = acc[i][j][r];
        if (fm) ((float*)C)[row * N + col] = v;
        else    ((unsigned short*)C)[row * N + col] = f2b(v);
      }
}

// ---------------------------------------------------------------------------
// Normalize Kb rows (64-elem L2 per (n,h)) in place (bf16); rho[bh,t] f32.
// One wave per (n,h).
// ---------------------------------------------------------------------------
__global__ __launch_bounds__(256)
void norm_rho(bf16_t* __restrict__ Kb, float* __restrict__ rho,
              const float* __restrict__ pf)
{
  const int g    = blockIdx.x * 4 + (threadIdx.x >> 6);
  const int lane = threadIdx.x & 63;
  const int n = g >> 4, h = g & 15;
  const size_t idx = (size_t)n * 1024 + h * 64 + lane;
  unsigned short* Kp = (unsigned short*)Kb;
  float kv = b2f(Kp[idx]);
  float ss = kv * kv;
#pragma unroll
  for (int m = 1; m < 64; m <<= 1) ss += __shfl_xor(ss, m);
  float kn = kv / fmaxf(sqrtf(ss), 1e-12f);
  Kp[idx] = f2b(kn);
  float s = kn;
#pragma unroll
  for (int m = 1; m < 64; m <<= 1) s += __shfl_xor(s, m);
  if (lane == 0) {
    float kbar = s * (1.f / 64.f);
    float gm = 1.f / (1.f + expf(-(pf[h]      * kbar + pf[16 + h])));
    float lm = 1.f / (1.f + expf(-(pf[32 + h] * kbar + pf[48 + h])));
    const int b = n >> 10, t = n & 1023;   // T = 1024
    rho[(size_t)(b * 16 + h) * 1024 + t] = (1.f - lm) * gm;
  }
}

// ---------------------------------------------------------------------------
// Stage one 64x64 bf16 chunk (rows = tokens) into LDS via DMA. 256 threads.
// ---------------------------------------------------------------------------
__device__ __forceinline__ void stage_chunk(const unsigned short* G, int n0c, int h,
                                            unsigned short* lds, int tid) {
#pragma unroll
  for (int sh = 0; sh < 2; ++sh) {
    const int idx = sh * 256 + tid;
    const int row = idx >> 3, col = (idx & 7) * 8;
    g2l16(G + (size_t)(n0c + row) * 1024 + h * 64 + col, lds + idx * 8);
  }
}

// Wave-0 prefix product of rho chunk -> aw (a_t), cw ((1-rho)/a).
__device__ __forceinline__ void rho_scan(const float* rho_s, float* aw, float* cw,
                                         int tid) {
  if (tid < 64) {
    const float r = rho_s[tid];
    float p = r;
#pragma unroll
    for (int d = 1; d < 64; d <<= 1) {
      float o = __shfl_up(p, d);
      if (tid >= d) p *= o;
    }
    aw[tid] = p;
    cw[tid] = (1.f - r) / p;
  }
}

// ---------------------------------------------------------------------------
// Pass 1: per (bh, chunk) block: U = sum_s (A_c/a_s)(1-rho_s) v_s k_s^T  (f32),
// A_g = A_c. 4 waves; wave w owns v-rows [16w,16w+16).
// ---------------------------------------------------------------------------
__global__ __launch_bounds__(256)
void chunk_outer(const unsigned short* __restrict__ Kb, const unsigned short* __restrict__ Vb,
                 const float* __restrict__ rho, float* __restrict__ Ug,
                 float* __restrict__ A_g)
{
  __shared__ __align__(16) unsigned short ks[4096];
  __shared__ __align__(16) unsigned short vs[4096];
  __shared__ float rho_s[64];
  __shared__ float aw[64], cw[64];
  const int tid = threadIdx.x;
  const int bid = blockIdx.x;
  const int bh = bid >> 4, c = bid & 15;
  const int b = bh >> 4, h = bh & 15;
  const int n0c = b * 1024 + c * 64;
  const int lane = tid & 63, wave = tid >> 6;
  const int quad = lane >> 4, tm = lane & 15;

  stage_chunk(Kb, n0c, h, ks, tid);
  stage_chunk(Vb, n0c, h, vs, tid);
  if (tid < 64) g2l4(rho + (size_t)bh * 1024 + c * 64 + tid, rho_s + tid);
  __syncthreads();
  rho_scan(rho_s, aw, cw, tid);
  __syncthreads();

  const __bf16* ksb = (const __bf16*)ks;
  const __bf16* vsb = (const __bf16*)vs;
  const float Ac = aw[63];
  const int wv = 16 * wave + tm;     // this lane's v-row (A-frag m)

#pragma unroll
  for (int j4 = 0; j4 < 4; ++j4) {   // kc tile
    const int kc = 16 * j4 + tm;
    f32x4 acc = (f32x4){0.f, 0.f, 0.f, 0.f};
#pragma unroll
    for (int kk = 0; kk < 2; ++kk) {
      const int kbase = kk * 32 + quad * 8;
      b16x8 af, bf;
#pragma unroll
      for (int j = 0; j < 8; ++j) {
        const int s = kbase + j;
        af[j] = vsb[s * 64 + wv];
        bf[j] = (__bf16)(Ac * cw[s] * (float)ksb[s * 64 + kc]);
      }
      acc = __builtin_amdgcn_mfma_f32_16x16x32_bf16(af, bf, acc, 0, 0, 0);
    }
#pragma unroll
    for (int r = 0; r < 4; ++r) {
      const int v = 16 * wave + quad * 4 + r;
      Ug[(size_t)bid * 4096 + v * 64 + 16 * j4 + tm] = acc[r];
    }
  }
  if (tid == 0) A_g[bid] = Ac;
}

// ---------------------------------------------------------------------------
// Pass 2: per-bh sequential chunk scan. S <- A_c*S + U_c, snapshot prefix (bf16).
// 64 blocks x 256 threads; thread owns 16 consecutive state elements.
// ---------------------------------------------------------------------------
__global__ __launch_bounds__(256)
void chunk_scan(const float* __restrict__ Ug, const float* __restrict__ A_g,
                unsigned short* __restrict__ Sp)
{
  const int bh = blockIdx.x;
  const int off = threadIdx.x * 16;
  float S[16];
#pragma unroll
  for (int i = 0; i < 16; ++i) S[i] = 0.f;

  for (int c = 0; c < 16; ++c) {
    const size_t base = ((size_t)bh * 16 + c) * 4096 + off;
    u16x8 o0, o1;
#pragma unroll
    for (int i = 0; i < 8; ++i) { o0[i] = f2b(S[i]); o1[i] = f2b(S[8 + i]); }
    *(u16x8*)(Sp + base)     = o0;
    *(u16x8*)(Sp + base + 8) = o1;
    const float Ac = A_g[bh * 16 + c];
#pragma unroll
    for (int i4 = 0; i4 < 4; ++i4) {
      const float4 u = *(const float4*)(Ug + base + i4 * 4);
      S[i4 * 4 + 0] = Ac * S[i4 * 4 + 0] + u.x;
      S[i4 * 4 + 1] = Ac * S[i4 * 4 + 1] + u.y;
      S[i4 * 4 + 2] = Ac * S[i4 * 4 + 2] + u.z;
      S[i4 * 4 + 3] = Ac * S[i4 * 4 + 3] + u.w;
    }
  }
}

// ---------------------------------------------------------------------------
// Pass 3: per (bh, chunk): P = Q V^T, decay-mask, Y = Pw*K + diag(a_t) Q S_prev.
// 4 waves; wave w owns t-rows [16w,16w+16). Y stored bf16.
// ---------------------------------------------------------------------------
__global__ __launch_bounds__(256)
void chunk_y(const unsigned short* __restrict__ Qb, const unsigned short* __restrict__ Kb,
             const unsigned short* __restrict__ Vb, const unsigned short* __restrict__ Sp,
             const float* __restrict__ rho, unsigned short* __restrict__ Yb)
{
  __shared__ __align__(16) unsigned short qs[4096];
  __shared__ __align__(16) unsigned short ks[4096];
  __shared__ __align__(16) unsigned short vs[4096];
  __shared__ __align__(16) unsigned short ss[4096];
  __shared__ __align__(16) unsigned short pt[4096];
  __shared__ float rho_s[64];
  __shared__ float aw[64], cw[64];
  const int tid = threadIdx.x;
  const int bid = blockIdx.x;
  const int bh = bid >> 4, c = bid & 15;
  const int b = bh >> 4, h = bh & 15;
  const int n0c = b * 1024 + c * 64;
  const int lane = tid & 63, wave = tid >> 6;
  const int quad = lane >> 4, tm = lane & 15;

  stage_chunk(Qb, n0c, h, qs, tid);
  stage_chunk(Kb, n0c, h, ks, tid);
  stage_chunk(Vb, n0c, h, vs, tid);
#pragma unroll
  for (int sh = 0; sh < 2; ++sh) {
    const int idx = sh * 256 + tid;
    g2l16(Sp + (size_t)bid * 4096 + idx * 8, ss + idx * 8);
  }
  if (tid < 64) g2l4(rho + (size_t)bh * 1024 + c * 64 + tid, rho_s + tid);
  __syncthreads();
  rho_scan(rho_s, aw, cw, tid);
  __syncthreads();

  const __bf16* qsb = (const __bf16*)qs;
  const __bf16* ksb = (const __bf16*)ks;
  const __bf16* vsb = (const __bf16*)vs;
  const __bf16* ssb = (const __bf16*)ss;
  __bf16* ptb = (__bf16*)pt;

  // A-fragments of Q for this wave's rows (t = 16w + tm)
  b16x8 af_q[2];
#pragma unroll
  for (int kk = 0; kk < 2; ++kk)
    af_q[kk] = *(const b16x8*)&qsb[(16 * wave + tm) * 64 + kk * 32 + quad * 8];

  // Phase A: P tiles + mask, write to wave-private pt rows
#pragma unroll
  for (int j4 = 0; j4 < 4; ++j4) {   // s tile
    f32x4 acc = (f32x4){0.f, 0.f, 0.f, 0.f};
#pragma unroll
    for (int kk = 0; kk < 2; ++kk) {
      const b16x8 bf = *(const b16x8*)&vsb[(16 * j4 + tm) * 64 + kk * 32 + quad * 8];
      acc = __builtin_amdgcn_mfma_f32_16x16x32_bf16(af_q[kk], bf, acc, 0, 0, 0);
    }
    const int s = 16 * j4 + tm;
    const float cws = cw[s];
#pragma unroll
    for (int r = 0; r < 4; ++r) {
      const int t = 16 * wave + quad * 4 + r;
      const float w = (s <= t) ? aw[t] * cws : 0.f;
      ptb[t * 64 + s] = (__bf16)(acc[r] * w);
    }
  }

  // Scaled Q fragment: a_t * q_t  (t = 16w + tm, row-uniform per lane)
  const float at = aw[16 * wave + tm];
  b16x8 af_qs[2], af_p[2];
#pragma unroll
  for (int kk = 0; kk < 2; ++kk) {
    b16x8 t8;
#pragma unroll
    for (int j = 0; j < 8; ++j) t8[j] = (__bf16)(at * (float)af_q[kk][j]);
    af_qs[kk] = t8;
    af_p[kk] = *(const b16x8*)&ptb[(16 * wave + tm) * 64 + kk * 32 + quad * 8];
  }

  // Phase B: Y = Pw*K + af_qs*Sprev (both accumulate into one C tile)
#pragma unroll
  for (int j4 = 0; j4 < 4; ++j4) {   // kc tile
    const int kc = 16 * j4 + tm;
    f32x4 acc = (f32x4){0.f, 0.f, 0.f, 0.f};
#pragma unroll
    for (int kk = 0; kk < 2; ++kk) {
      const int kbase = kk * 32 + quad * 8;
      b16x8 bk, bs;
#pragma unroll
      for (int j = 0; j < 8; ++j) {
        bk[j] = ksb[(kbase + j) * 64 + kc];
        bs[j] = ssb[(kbase + j) * 64 + kc];
      }
      acc = __builtin_amdgcn_mfma_f32_16x16x32_bf16(af_p[kk],  bk, acc, 0, 0, 0);
      acc = __builtin_amdgcn_mfma_f32_16x16x32_bf16(af_qs[kk], bs, acc, 0, 0, 0);
    }
#pragma unroll
    for (int r = 0; r < 4; ++r) {
      const int t = 16 * wave + quad * 4 + r;
      Yb[(size_t)(n0c + t) * 1024 + h * 64 + kc] = f2b(acc[r]);
    }
  }
}

// ---------------------------------------------------------------------------
extern "C" void kernel_launch(void* const* d_in, const int* in_sizes, int n_in,
                              void* d_out, int out_size, void* d_ws, size_t ws_size,
                              hipStream_t stream) {
  const void* x  = d_in[0];
  const void* Wq = d_in[1];
  const void* Wk = d_in[2];
  const void* Wv = d_in[3];
  const void* Wo = d_in[4];

  char* ws = (char*)d_ws;
  const size_t MB = 1ull << 20;
  bf16_t* x_b  = (bf16_t*)(ws);
  bf16_t* Wq_b = (bf16_t*)(ws + 8 * MB);
  bf16_t* Wk_b = (bf16_t*)(ws + 10 * MB);
  bf16_t* Wv_b = (bf16_t*)(ws + 12 * MB);
  bf16_t* Wo_b = (bf16_t*)(ws + 14 * MB);
  unsigned short* Qb = (unsigned short*)(ws + 16 * MB);
  unsigned short* Kb = (unsigned short*)(ws + 24 * MB);
  unsigned short* Vb = (unsigned short*)(ws + 32 * MB);
  unsigned short* Yb = (unsigned short*)(ws + 40 * MB);
  float*  Ug   = (float*)(ws + 48 * MB);
  unsigned short* Sp = (unsigned short*)(ws + 64 * MB);
  float*  rh   = (float*)(ws + 72 * MB);
  float*  A_g  = (float*)(ws + 72 * MB + 256 * 1024);
  float*  pf   = (float*)(ws + 73 * MB);
  int*    flag = (int*)(ws + 73 * MB + 1024);

  detect_dtype<<<1, 64, 0, stream>>>((const unsigned*)x, flag);

  convert_bf16<<<2048, 256, 0, stream>>>(x,  x_b,  4096 * 1024, flag);
  convert_bf16<<<512,  256, 0, stream>>>(Wq, Wq_b, 1024 * 1024, flag);
  convert_bf16<<<512,  256, 0, stream>>>(Wk, Wk_b, 1024 * 1024, flag);
  convert_bf16<<<512,  256, 0, stream>>>(Wv, Wv_b, 1024 * 1024, flag);
  convert_bf16<<<512,  256, 0, stream>>>(Wo, Wo_b, 1024 * 1024, flag);
  conv_params<<<1, 64, 0, stream>>>(d_in[5], d_in[6], d_in[7], d_in[8], pf, flag);

  dim3 blk(256);
  gemm_qkv<<<dim3(8, 32, 3), blk, 0, stream>>>(x_b, Wq_b, Wk_b, Wv_b,
                                               (bf16_t*)Qb, (bf16_t*)Kb, (bf16_t*)Vb,
                                               4096, 1024, 1024);
  norm_rho<<<dim3(16384), blk, 0, stream>>>((bf16_t*)Kb, rh, pf);
  chunk_outer<<<dim3(1024), blk, 0, stream>>>(Kb, Vb, rh, Ug, A_g);
  chunk_scan<<<dim3(64), blk, 0, stream>>>(Ug, A_g, Sp);
  chunk_y<<<dim3(1024), blk, 0, stream>>>(Qb, Kb, Vb, Sp, rh, Yb);
  gemm_out<<<dim3(8, 32, 1), blk, 0, stream>>>((const bf16_t*)Yb, Wo_b, d_out,
                                               4096, 1024, 1024, flag);
}

// Round 4
// 183.965 us; speedup vs baseline: 4.1720x; 1.1660x over previous
//
#include <hip/hip_runtime.h>
#include <hip/hip_bf16.h>

// STPT-Light: x->(Q,K,V) proj (fused K-norm+rho), chunked linear-attn (MFMA), out proj.
// B=4 T=1024 D=1024 H=16 DK=64. Chunk C=64, 16 chunks, 64 (b,h) pairs.
//
// ws layout (MB): 0 x_b[8] | 8 Wq_b[2] 10 Wk_b[2] 12 Wv_b[2] 14 Wo_b[2]
//   16 Qb[8] 24 Kb[8] 32 Vb[8] 40 Yb[8]  (bf16 4096x1024)
//   48 U[16] (f32 64bh x 16c x 64 x 64)
//   64 Sprev[8] (bf16 64bh x 16c x 64 x 64)
//   72 rho[256KB f32]

typedef __bf16 b16x8 __attribute__((ext_vector_type(8)));
typedef float  f32x4 __attribute__((ext_vector_type(4)));
typedef unsigned short u16x8 __attribute__((ext_vector_type(8)));
using bf16_t = __hip_bfloat16;

#define AS1C(p) ((const __attribute__((address_space(1))) void*)(p))
#define AS3(p)  ((__attribute__((address_space(3))) void*)(p))

__device__ __forceinline__ void g2l16(const void* g, void* l) {
  __builtin_amdgcn_global_load_lds(AS1C(g), AS3(l), 16, 0, 0);
}
__device__ __forceinline__ void g2l4(const void* g, void* l) {
  __builtin_amdgcn_global_load_lds(AS1C(g), AS3(l), 4, 0, 0);
}

__device__ __forceinline__ unsigned short f2b(float x) {  // RNE f32->bf16 bits
  unsigned u = __float_as_uint(x);
  return (unsigned short)((u + 0x7FFFu + ((u >> 16) & 1u)) >> 16);
}
__device__ __forceinline__ float b2f(unsigned short b) {
  return __uint_as_float(((unsigned)b) << 16);
}

// Wire-format detector: f32 N(0,1) words have exponent field in [95,135];
// bf16 pairs reinterpreted land ~[240,255]. Every wave computes identically.
__device__ __forceinline__ int wire_flag(const unsigned* __restrict__ x, int tid) {
  unsigned u = x[tid & 63];
  int e = (int)((u >> 23) & 0xFF);
  unsigned long long m = __ballot(e >= 95 && e <= 135);
  return (__popcll(m) >= 32) ? 1 : 0;   // 1 = f32 wire
}

// ---------------------------------------------------------------------------
// Fused conversion of all 5 input tensors to bf16 (or passthrough copy).
// 8M elements total, 8/thread -> 4096 blocks.
// ---------------------------------------------------------------------------
__global__ __launch_bounds__(256)
void convert_all(const void* __restrict__ x,
                 const void* __restrict__ w0, const void* __restrict__ w1,
                 const void* __restrict__ w2, const void* __restrict__ w3,
                 unsigned short* __restrict__ xb,
                 unsigned short* __restrict__ wb0, unsigned short* __restrict__ wb1,
                 unsigned short* __restrict__ wb2, unsigned short* __restrict__ wb3)
{
  const int fm = wire_flag((const unsigned*)x, threadIdx.x);
  const long i8 = ((long)blockIdx.x * 256 + threadIdx.x) * 8;
  const void* src; unsigned short* dst; long off;
  if (i8 < 4194304) { src = x; dst = xb; off = i8; }
  else {
    long j = i8 - 4194304;
    int w = (int)(j >> 20); off = j & 1048575;
    src = (w == 0) ? w0 : (w == 1) ? w1 : (w == 2) ? w2 : w3;
    dst = (w == 0) ? wb0 : (w == 1) ? wb1 : (w == 2) ? wb2 : wb3;
  }
  if (fm) {
    const float4 a = *(const float4*)((const float*)src + off);
    const float4 b = *(const float4*)((const float*)src + off + 4);
    u16x8 o;
    o[0] = f2b(a.x); o[1] = f2b(a.y); o[2] = f2b(a.z); o[3] = f2b(a.w);
    o[4] = f2b(b.x); o[5] = f2b(b.y); o[6] = f2b(b.z); o[7] = f2b(b.w);
    *(u16x8*)(dst + off) = o;
  } else {
    *(int4*)(dst + off) = *(const int4*)((const unsigned short*)src + off);
  }
}

// ---------------------------------------------------------------------------
// Fused Q/K/V projection: z selects weight/output. C[m,n]=sum_k A[m,k]B[n,k].
// 128x128 tile, BK=32, m97 structure + source-side chunk swizzle (2-way free).
// z==1 (K): epilogue does per-(token,head) L2-norm from the f32 accumulator
// and writes rho.
// ---------------------------------------------------------------------------
__global__ __launch_bounds__(256)
void gemm_qkv(const unsigned* __restrict__ xraw,
              const bf16_t* __restrict__ A,
              const bf16_t* __restrict__ B0, const bf16_t* __restrict__ B1,
              const bf16_t* __restrict__ B2,
              unsigned short* __restrict__ C0, unsigned short* __restrict__ C1,
              unsigned short* __restrict__ C2,
              const void* __restrict__ Wg, const void* __restrict__ bg,
              const void* __restrict__ Wl, const void* __restrict__ bl,
              float* __restrict__ rho)
{
  constexpr int K = 1024, N = 1024;
  const int z = blockIdx.z;
  const bf16_t* B = (z == 0) ? B0 : (z == 1) ? B1 : B2;
  unsigned short* C = (z == 0) ? C0 : (z == 1) ? C1 : C2;
  __shared__ __align__(16) unsigned short As[128 * 32];
  __shared__ __align__(16) unsigned short Bs[128 * 32];
  const int tid  = threadIdx.x;
  const int lane = tid & 63;
  const int wave = tid >> 6;
  const int wm = wave >> 1, wn = wave & 1;
  const int quad = lane >> 4, tm = lane & 15;
  const long row0 = (long)blockIdx.y * 128;
  const long col0 = (long)blockIdx.x * 128;

  f32x4 acc[4][4];
#pragma unroll
  for (int i = 0; i < 4; ++i)
#pragma unroll
    for (int j = 0; j < 4; ++j) acc[i][j] = (f32x4){0.f, 0.f, 0.f, 0.f};

  // staging: LDS chunk tid holds global k-chunk qg = (scc - (sr>>1)) & 3
  const int sr = tid >> 2;
  const int scc = tid & 3;
  const int qg = (scc - (sr >> 1)) & 3;
  const bf16_t* ap = A + (row0 + sr) * (long)K + qg * 8;
  const bf16_t* bp = B + (col0 + sr) * (long)K + qg * 8;
  unsigned short* la = As + tid * 8;
  unsigned short* lb = Bs + tid * 8;
  // read side: chunk slot for global chunk `quad` in row m is (quad+(m>>1))&3
  const int cc = (quad + ((tm >> 1) & 3)) & 3;

  for (int kt = 0; kt < K; kt += 32) {
    __syncthreads();
    g2l16(ap + kt,           la);
    g2l16(ap + 64l * K + kt, la + 2048);
    g2l16(bp + kt,           lb);
    g2l16(bp + 64l * K + kt, lb + 2048);
    __syncthreads();

    b16x8 af[4], bfr[4];
#pragma unroll
    for (int i = 0; i < 4; ++i)
      af[i] = *(const b16x8*)&As[(wm * 64 + i * 16 + tm) * 32 + cc * 8];
#pragma unroll
    for (int j = 0; j < 4; ++j)
      bfr[j] = *(const b16x8*)&Bs[(wn * 64 + j * 16 + tm) * 32 + cc * 8];
#pragma unroll
    for (int i = 0; i < 4; ++i)
#pragma unroll
      for (int j = 0; j < 4; ++j)
        acc[i][j] = __builtin_amdgcn_mfma_f32_16x16x32_bf16(af[i], bfr[j], acc[i][j], 0, 0, 0);
  }

  // C/D layout (m89-verified): col = lane&15, row = (lane>>4)*4 + reg
  if (z != 1) {
#pragma unroll
    for (int i = 0; i < 4; ++i)
#pragma unroll
      for (int j = 0; j < 4; ++j)
#pragma unroll
        for (int r = 0; r < 4; ++r) {
          long row = row0 + wm * 64 + i * 16 + quad * 4 + r;
          long col = col0 + wn * 64 + j * 16 + tm;
          C[row * N + col] = f2b(acc[i][j][r]);
        }
  } else {
    // K path: L2-normalize each row's 64 head-dims (held across the 16 tm
    // lanes of this quad x 4 j-tiles), then rho from kbar.
    const int fm = wire_flag(xraw, tid);
    const int h = blockIdx.x * 2 + wn;
    float wgv, bgv, wlv, blv;
    if (fm) {
      wgv = ((const float*)Wg)[h]; bgv = ((const float*)bg)[h];
      wlv = ((const float*)Wl)[h]; blv = ((const float*)bl)[h];
    } else {
      wgv = b2f(((const unsigned short*)Wg)[h]); bgv = b2f(((const unsigned short*)bg)[h]);
      wlv = b2f(((const unsigned short*)Wl)[h]); blv = b2f(((const unsigned short*)bl)[h]);
    }
#pragma unroll
    for (int i = 0; i < 4; ++i)
#pragma unroll
      for (int r = 0; r < 4; ++r) {
        float ss = 0.f, sv = 0.f;
#pragma unroll
        for (int j = 0; j < 4; ++j) {
          const float v = acc[i][j][r];
          ss += v * v; sv += v;
        }
#pragma unroll
        for (int m = 1; m < 16; m <<= 1) {   // reduce across the 16 tm lanes
          ss += __shfl_xor(ss, m);
          sv += __shfl_xor(sv, m);
        }
        const float inv = 1.f / fmaxf(sqrtf(ss), 1e-12f);
        const long row = row0 + wm * 64 + i * 16 + quad * 4 + r;
#pragma unroll
        for (int j = 0; j < 4; ++j)
          C[row * N + col0 + wn * 64 + j * 16 + tm] = f2b(acc[i][j][r] * inv);
        if (tm == 0) {
          const float kbar = sv * inv * (1.f / 64.f);
          const float gm = 1.f / (1.f + expf(-(wgv * kbar + bgv)));
          const float lm = 1.f / (1.f + expf(-(wlv * kbar + blv)));
          const int b = (int)(row >> 10), t = (int)(row & 1023);
          rho[(size_t)(b * 16 + h) * 1024 + t] = (1.f - lm) * gm;
        }
      }
  }
}

// ---------------------------------------------------------------------------
// Output GEMM: 64x64 tile, BK=64, 4 waves (wave w owns cols 16w..16w+16).
// Grid 16x64 = 1024 blocks = 4/CU (latency hiding). Swizzled staging.
// Runtime-flagged f32/bf16 store.
// ---------------------------------------------------------------------------
__global__ __launch_bounds__(256)
void gemm_out64(const unsigned* __restrict__ xraw,
                const bf16_t* __restrict__ A, const bf16_t* __restrict__ B,
                void* __restrict__ C)
{
  constexpr int K = 1024, N = 1024;
  __shared__ __align__(16) unsigned short As[64 * 64];   // [kk][row][32]
  __shared__ __align__(16) unsigned short Bs[64 * 64];
  const int tid  = threadIdx.x;
  const int lane = tid & 63;
  const int wave = tid >> 6;
  const int quad = lane >> 4, tm = lane & 15;
  const long row0 = (long)blockIdx.y * 64;
  const long col0 = (long)blockIdx.x * 64;

  f32x4 acc[4];
#pragma unroll
  for (int i = 0; i < 4; ++i) acc[i] = (f32x4){0.f, 0.f, 0.f, 0.f};

  const int sr = tid >> 2;
  const int scc = tid & 3;
  const int qg = (scc - (sr >> 1)) & 3;
  const bf16_t* ap = A + (row0 + sr) * (long)K + qg * 8;
  const bf16_t* bp = B + (col0 + sr) * (long)K + qg * 8;
  unsigned short* la = As + tid * 8;
  unsigned short* lb = Bs + tid * 8;
  const int cc = (quad + ((tm >> 1) & 3)) & 3;

  for (int kt = 0; kt < K; kt += 64) {
    __syncthreads();
    g2l16(ap + kt,      la);
    g2l16(ap + kt + 32, la + 2048);
    g2l16(bp + kt,      lb);
    g2l16(bp + kt + 32, lb + 2048);
    __syncthreads();

    b16x8 bf0 = *(const b16x8*)&Bs[(wave * 16 + tm) * 32 + cc * 8];
    b16x8 bf1 = *(const b16x8*)&Bs[2048 + (wave * 16 + tm) * 32 + cc * 8];
#pragma unroll
    for (int i = 0; i < 4; ++i) {
      b16x8 a0 = *(const b16x8*)&As[(i * 16 + tm) * 32 + cc * 8];
      b16x8 a1 = *(const b16x8*)&As[2048 + (i * 16 + tm) * 32 + cc * 8];
      acc[i] = __builtin_amdgcn_mfma_f32_16x16x32_bf16(a0, bf0, acc[i], 0, 0, 0);
      acc[i] = __builtin_amdgcn_mfma_f32_16x16x32_bf16(a1, bf1, acc[i], 0, 0, 0);
    }
  }

  const int fm = wire_flag(xraw, tid);
#pragma unroll
  for (int i = 0; i < 4; ++i)
#pragma unroll
    for (int r = 0; r < 4; ++r) {
      const long row = row0 + i * 16 + quad * 4 + r;
      const long col = col0 + wave * 16 + tm;
      const float v = acc[i][r];
      if (fm) ((float*)C)[row * N + col] = v;
      else    ((unsigned short*)C)[row * N + col] = f2b(v);
    }
}

// ---------------------------------------------------------------------------
// Stage one 64x64 bf16 chunk (rows = tokens) into LDS via DMA. 256 threads.
// ---------------------------------------------------------------------------
__device__ __forceinline__ void stage_chunk(const unsigned short* G, int n0c, int h,
                                            unsigned short* lds, int tid) {
#pragma unroll
  for (int sh = 0; sh < 2; ++sh) {
    const int idx = sh * 256 + tid;
    const int row = idx >> 3, col = (idx & 7) * 8;
    g2l16(G + (size_t)(n0c + row) * 1024 + h * 64 + col, lds + idx * 8);
  }
}

// Wave-0 prefix product of rho chunk -> aw (a_t), cw ((1-rho)/a).
__device__ __forceinline__ void rho_scan(const float* rho_s, float* aw, float* cw,
                                         int tid) {
  if (tid < 64) {
    const float r = rho_s[tid];
    float p = r;
#pragma unroll
    for (int d = 1; d < 64; d <<= 1) {
      float o = __shfl_up(p, d);
      if (tid >= d) p *= o;
    }
    aw[tid] = p;
    cw[tid] = (1.f - r) / p;
  }
}

// ---------------------------------------------------------------------------
// Pass 1: per (bh, chunk) block: U = sum_s (A_c/a_s)(1-rho_s) v_s k_s^T (f32).
// ---------------------------------------------------------------------------
__global__ __launch_bounds__(256)
void chunk_outer(const unsigned short* __restrict__ Kb, const unsigned short* __restrict__ Vb,
                 const float* __restrict__ rho, float* __restrict__ Ug,
                 float* __restrict__ A_g)
{
  __shared__ __align__(16) unsigned short ks[4096];
  __shared__ __align__(16) unsigned short vs[4096];
  __shared__ float rho_s[64];
  __shared__ float aw[64], cw[64];
  const int tid = threadIdx.x;
  const int bid = blockIdx.x;
  const int bh = bid >> 4, c = bid & 15;
  const int b = bh >> 4, h = bh & 15;
  const int n0c = b * 1024 + c * 64;
  const int lane = tid & 63, wave = tid >> 6;
  const int quad = lane >> 4, tm = lane & 15;

  stage_chunk(Kb, n0c, h, ks, tid);
  stage_chunk(Vb, n0c, h, vs, tid);
  if (tid < 64) g2l4(rho + (size_t)bh * 1024 + c * 64 + tid, rho_s + tid);
  __syncthreads();
  rho_scan(rho_s, aw, cw, tid);
  __syncthreads();

  const __bf16* ksb = (const __bf16*)ks;
  const __bf16* vsb = (const __bf16*)vs;
  const float Ac = aw[63];
  const int wv = 16 * wave + tm;     // this lane's v-row (A-frag m)

#pragma unroll
  for (int j4 = 0; j4 < 4; ++j4) {   // kc tile
    const int kc = 16 * j4 + tm;
    f32x4 acc = (f32x4){0.f, 0.f, 0.f, 0.f};
#pragma unroll
    for (int kk = 0; kk < 2; ++kk) {
      const int kbase = kk * 32 + quad * 8;
      b16x8 af, bf;
#pragma unroll
      for (int j = 0; j < 8; ++j) {
        const int s = kbase + j;
        af[j] = vsb[s * 64 + wv];
        bf[j] = (__bf16)(Ac * cw[s] * (float)ksb[s * 64 + kc]);
      }
      acc = __builtin_amdgcn_mfma_f32_16x16x32_bf16(af, bf, acc, 0, 0, 0);
    }
#pragma unroll
    for (int r = 0; r < 4; ++r) {
      const int v = 16 * wave + quad * 4 + r;
      Ug[(size_t)bid * 4096 + v * 64 + 16 * j4 + tm] = acc[r];
    }
  }
  if (tid == 0) A_g[bid] = Ac;
}

// ---------------------------------------------------------------------------
// Pass 2: per-bh sequential chunk scan. S <- A_c*S + U_c, snapshot prefix (bf16).
// ---------------------------------------------------------------------------
__global__ __launch_bounds__(256)
void chunk_scan(const float* __restrict__ Ug, const float* __restrict__ A_g,
                unsigned short* __restrict__ Sp)
{
  const int bh = blockIdx.x;
  const int off = threadIdx.x * 16;
  float S[16];
#pragma unroll
  for (int i = 0; i < 16; ++i) S[i] = 0.f;

  for (int c = 0; c < 16; ++c) {
    const size_t base = ((size_t)bh * 16 + c) * 4096 + off;
    u16x8 o0, o1;
#pragma unroll
    for (int i = 0; i < 8; ++i) { o0[i] = f2b(S[i]); o1[i] = f2b(S[8 + i]); }
    *(u16x8*)(Sp + base)     = o0;
    *(u16x8*)(Sp + base + 8) = o1;
    const float Ac = A_g[bh * 16 + c];
#pragma unroll
    for (int i4 = 0; i4 < 4; ++i4) {
      const float4 u = *(const float4*)(Ug + base + i4 * 4);
      S[i4 * 4 + 0] = Ac * S[i4 * 4 + 0] + u.x;
      S[i4 * 4 + 1] = Ac * S[i4 * 4 + 1] + u.y;
      S[i4 * 4 + 2] = Ac * S[i4 * 4 + 2] + u.z;
      S[i4 * 4 + 3] = Ac * S[i4 * 4 + 3] + u.w;
    }
  }
}

// ---------------------------------------------------------------------------
// Pass 3: per (bh, chunk): P = Q V^T, decay-mask, Y = Pw*K + diag(a_t) Q S_prev.
// ---------------------------------------------------------------------------
__global__ __launch_bounds__(256)
void chunk_y(const unsigned short* __restrict__ Qb, const unsigned short* __restrict__ Kb,
             const unsigned short* __restrict__ Vb, const unsigned short* __restrict__ Sp,
             const float* __restrict__ rho, unsigned short* __restrict__ Yb)
{
  __shared__ __align__(16) unsigned short qs[4096];
  __shared__ __align__(16) unsigned short ks[4096];
  __shared__ __align__(16) unsigned short vs[4096];
  __shared__ __align__(16) unsigned short ss[4096];
  __shared__ __align__(16) unsigned short pt[4096];
  __shared__ float rho_s[64];
  __shared__ float aw[64], cw[64];
  const int tid = threadIdx.x;
  const int bid = blockIdx.x;
  const int bh = bid >> 4, c = bid & 15;
  const int b = bh >> 4, h = bh & 15;
  const int n0c = b * 1024 + c * 64;
  const int lane = tid & 63, wave = tid >> 6;
  const int quad = lane >> 4, tm = lane & 15;

  stage_chunk(Qb, n0c, h, qs, tid);
  stage_chunk(Kb, n0c, h, ks, tid);
  stage_chunk(Vb, n0c, h, vs, tid);
#pragma unroll
  for (int sh = 0; sh < 2; ++sh) {
    const int idx = sh * 256 + tid;
    g2l16(Sp + (size_t)bid * 4096 + idx * 8, ss + idx * 8);
  }
  if (tid < 64) g2l4(rho + (size_t)bh * 1024 + c * 64 + tid, rho_s + tid);
  __syncthreads();
  rho_scan(rho_s, aw, cw, tid);
  __syncthreads();

  const __bf16* qsb = (const __bf16*)qs;
  const __bf16* ksb = (const __bf16*)ks;
  const __bf16* vsb = (const __bf16*)vs;
  const __bf16* ssb = (const __bf16*)ss;
  __bf16* ptb = (__bf16*)pt;

  // A-fragments of Q for this wave's rows (t = 16w + tm)
  b16x8 af_q[2];
#pragma unroll
  for (int kk = 0; kk < 2; ++kk)
    af_q[kk] = *(const b16x8*)&qsb[(16 * wave + tm) * 64 + kk * 32 + quad * 8];

  // Phase A: P tiles + mask, write to wave-private pt rows
#pragma unroll
  for (int j4 = 0; j4 < 4; ++j4) {   // s tile
    f32x4 acc = (f32x4){0.f, 0.f, 0.f, 0.f};
#pragma unroll
    for (int kk = 0; kk < 2; ++kk) {
      const b16x8 bf = *(const b16x8*)&vsb[(16 * j4 + tm) * 64 + kk * 32 + quad * 8];
      acc = __builtin_amdgcn_mfma_f32_16x16x32_bf16(af_q[kk], bf, acc, 0, 0, 0);
    }
    const int s = 16 * j4 + tm;
    const float cws = cw[s];
#pragma unroll
    for (int r = 0; r < 4; ++r) {
      const int t = 16 * wave + quad * 4 + r;
      const float w = (s <= t) ? aw[t] * cws : 0.f;
      ptb[t * 64 + s] = (__bf16)(acc[r] * w);
    }
  }

  // Scaled Q fragment: a_t * q_t  (t = 16w + tm, row-uniform per lane)
  const float at = aw[16 * wave + tm];
  b16x8 af_qs[2], af_p[2];
#pragma unroll
  for (int kk = 0; kk < 2; ++kk) {
    b16x8 t8;
#pragma unroll
    for (int j = 0; j < 8; ++j) t8[j] = (__bf16)(at * (float)af_q[kk][j]);
    af_qs[kk] = t8;
    af_p[kk] = *(const b16x8*)&ptb[(16 * wave + tm) * 64 + kk * 32 + quad * 8];
  }

  // Phase B: Y = Pw*K + af_qs*Sprev (both accumulate into one C tile)
#pragma unroll
  for (int j4 = 0; j4 < 4; ++j4) {   // kc tile
    const int kc = 16 * j4 + tm;
    f32x4 acc = (f32x4){0.f, 0.f, 0.f, 0.f};
#pragma unroll
    for (int kk = 0; kk < 2; ++kk) {
      const int kbase = kk * 32 + quad * 8;
      b16x8 bk, bs;
#pragma unroll
      for (int j = 0; j < 8; ++j) {
        bk[j] = ksb[(kbase + j) * 64 + kc];
        bs[j] = ssb[(kbase + j) * 64 + kc];
      }
      acc = __builtin_amdgcn_mfma_f32_16x16x32_bf16(af_p[kk],  bk, acc, 0, 0, 0);
      acc = __builtin_amdgcn_mfma_f32_16x16x32_bf16(af_qs[kk], bs, acc, 0, 0, 0);
    }
#pragma unroll
    for (int r = 0; r < 4; ++r) {
      const int t = 16 * wave + quad * 4 + r;
      Yb[(size_t)(n0c + t) * 1024 + h * 64 + kc] = f2b(acc[r]);
    }
  }
}

// ---------------------------------------------------------------------------
extern "C" void kernel_launch(void* const* d_in, const int* in_sizes, int n_in,
                              void* d_out, int out_size, void* d_ws, size_t ws_size,
                              hipStream_t stream) {
  const void* x  = d_in[0];
  const void* Wq = d_in[1];
  const void* Wk = d_in[2];
  const void* Wv = d_in[3];
  const void* Wo = d_in[4];

  char* ws = (char*)d_ws;
  const size_t MB = 1ull << 20;
  unsigned short* x_b  = (unsigned short*)(ws);
  unsigned short* Wq_b = (unsigned short*)(ws + 8 * MB);
  unsigned short* Wk_b = (unsigned short*)(ws + 10 * MB);
  unsigned short* Wv_b = (unsigned short*)(ws + 12 * MB);
  unsigned short* Wo_b = (unsigned short*)(ws + 14 * MB);
  unsigned short* Qb = (unsigned short*)(ws + 16 * MB);
  unsigned short* Kb = (unsigned short*)(ws + 24 * MB);
  unsigned short* Vb = (unsigned short*)(ws + 32 * MB);
  unsigned short* Yb = (unsigned short*)(ws + 40 * MB);
  float*  Ug   = (float*)(ws + 48 * MB);
  unsigned short* Sp = (unsigned short*)(ws + 64 * MB);
  float*  rh   = (float*)(ws + 72 * MB);
  float*  A_g  = (float*)(ws + 72 * MB + 256 * 1024);

  dim3 blk(256);
  convert_all<<<dim3(4096), blk, 0, stream>>>(x, Wq, Wk, Wv, Wo,
                                              x_b, Wq_b, Wk_b, Wv_b, Wo_b);
  gemm_qkv<<<dim3(8, 32, 3), blk, 0, stream>>>((const unsigned*)x,
      (const bf16_t*)x_b, (const bf16_t*)Wq_b, (const bf16_t*)Wk_b, (const bf16_t*)Wv_b,
      Qb, Kb, Vb, d_in[5], d_in[6], d_in[7], d_in[8], rh);
  chunk_outer<<<dim3(1024), blk, 0, stream>>>(Kb, Vb, rh, Ug, A_g);
  chunk_scan<<<dim3(64), blk, 0, stream>>>(Ug, A_g, Sp);
  chunk_y<<<dim3(1024), blk, 0, stream>>>(Qb, Kb, Vb, Sp, rh, Yb);
  gemm_out64<<<dim3(16, 64), blk, 0, stream>>>((const unsigned*)x,
      (const bf16_t*)Yb, (const bf16_t*)Wo_b, d_out);
}

// Round 5
// 168.911 us; speedup vs baseline: 4.5438x; 1.0891x over previous
//
#include <hip/hip_runtime.h>
#include <hip/hip_bf16.h>

// STPT-Light: x->(Q,K,V) proj (fused K-norm+rho), chunked linear-attn (MFMA), out proj.
// B=4 T=1024 D=1024 H=16 DK=64. Chunk C=64, 16 chunks, 64 (b,h) pairs.
//
// ws layout (MB): 0 x_b[8] | 8 Wq_b[2] 10 Wk_b[2] 12 Wv_b[2] 14 Wo_b[2]
//   16 Qb[8] 24 Kb[8] 32 Vb[8] 40 Yb[8]  (bf16 4096x1024)
//   48 Ug[8]  (bf16 U^T: 64bh x 16c x [kc][v])
//   64 Sp[8]  (bf16 S^T snapshots, same indexing)
//   72 rho[256KB f32] | +256KB A_g[4KB]

typedef __bf16 b16x8 __attribute__((ext_vector_type(8)));
typedef float  f32x4 __attribute__((ext_vector_type(4)));
typedef unsigned short u16x8 __attribute__((ext_vector_type(8)));
using bf16_t = __hip_bfloat16;

#define AS1C(p) ((const __attribute__((address_space(1))) void*)(p))
#define AS3(p)  ((__attribute__((address_space(3))) void*)(p))

__device__ __forceinline__ void g2l16(const void* g, void* l) {
  __builtin_amdgcn_global_load_lds(AS1C(g), AS3(l), 16, 0, 0);
}
__device__ __forceinline__ void g2l4(const void* g, void* l) {
  __builtin_amdgcn_global_load_lds(AS1C(g), AS3(l), 4, 0, 0);
}

__device__ __forceinline__ unsigned short f2b(float x) {  // RNE f32->bf16 bits
  unsigned u = __float_as_uint(x);
  return (unsigned short)((u + 0x7FFFu + ((u >> 16) & 1u)) >> 16);
}
__device__ __forceinline__ float b2f(unsigned short b) {
  return __uint_as_float(((unsigned)b) << 16);
}

// Wire-format detector: f32 N(0,1) words have exponent field in [95,135].
__device__ __forceinline__ int wire_flag(const unsigned* __restrict__ x, int tid) {
  unsigned u = x[tid & 63];
  int e = (int)((u >> 23) & 0xFF);
  unsigned long long m = __ballot(e >= 95 && e <= 135);
  return (__popcll(m) >= 32) ? 1 : 0;   // 1 = f32 wire
}

// ---------------------------------------------------------------------------
// Fused conversion of all 5 input tensors to bf16 (or passthrough copy).
// ---------------------------------------------------------------------------
__global__ __launch_bounds__(256)
void convert_all(const void* __restrict__ x,
                 const void* __restrict__ w0, const void* __restrict__ w1,
                 const void* __restrict__ w2, const void* __restrict__ w3,
                 unsigned short* __restrict__ xb,
                 unsigned short* __restrict__ wb0, unsigned short* __restrict__ wb1,
                 unsigned short* __restrict__ wb2, unsigned short* __restrict__ wb3)
{
  const int fm = wire_flag((const unsigned*)x, threadIdx.x);
  const long i8 = ((long)blockIdx.x * 256 + threadIdx.x) * 8;
  const void* src; unsigned short* dst; long off;
  if (i8 < 4194304) { src = x; dst = xb; off = i8; }
  else {
    long j = i8 - 4194304;
    int w = (int)(j >> 20); off = j & 1048575;
    src = (w == 0) ? w0 : (w == 1) ? w1 : (w == 2) ? w2 : w3;
    dst = (w == 0) ? wb0 : (w == 1) ? wb1 : (w == 2) ? wb2 : wb3;
  }
  if (fm) {
    const float4 a = *(const float4*)((const float*)src + off);
    const float4 b = *(const float4*)((const float*)src + off + 4);
    u16x8 o;
    o[0] = f2b(a.x); o[1] = f2b(a.y); o[2] = f2b(a.z); o[3] = f2b(a.w);
    o[4] = f2b(b.x); o[5] = f2b(b.y); o[6] = f2b(b.z); o[7] = f2b(b.w);
    *(u16x8*)(dst + off) = o;
  } else {
    *(int4*)(dst + off) = *(const int4*)((const unsigned short*)src + off);
  }
}

// ---------------------------------------------------------------------------
// Fused Q/K/V projection. 128x128 tile, BK=32, m97 structure, source swizzle.
// XCD patch decode: each XCD owns a 4x8 tile patch (~3MB working set in L2).
// z==1 (K): epilogue L2-norm + rho.
// ---------------------------------------------------------------------------
__global__ __launch_bounds__(256)
void gemm_qkv(const unsigned* __restrict__ xraw,
              const bf16_t* __restrict__ A,
              const bf16_t* __restrict__ B0, const bf16_t* __restrict__ B1,
              const bf16_t* __restrict__ B2,
              unsigned short* __restrict__ C0, unsigned short* __restrict__ C1,
              unsigned short* __restrict__ C2,
              const void* __restrict__ Wg, const void* __restrict__ bg,
              const void* __restrict__ Wl, const void* __restrict__ bl,
              float* __restrict__ rho)
{
  constexpr int K = 1024, N = 1024;
  // XCD-aware decode: flat -> (z, bx, by) with xcd = flat&7 owning a 4x8 patch
  const int flat = blockIdx.x;
  const int xcd = flat & 7, sl = flat >> 3;
  const int z = sl >> 5, t5 = sl & 31;
  const int bx = ((xcd & 1) << 2) | (t5 & 3);
  const int by = ((xcd >> 1) << 3) | (t5 >> 2);
  const bf16_t* B = (z == 0) ? B0 : (z == 1) ? B1 : B2;
  unsigned short* C = (z == 0) ? C0 : (z == 1) ? C1 : C2;
  __shared__ __align__(16) unsigned short As[128 * 32];
  __shared__ __align__(16) unsigned short Bs[128 * 32];
  const int tid  = threadIdx.x;
  const int lane = tid & 63;
  const int wave = tid >> 6;
  const int wm = wave >> 1, wn = wave & 1;
  const int quad = lane >> 4, tm = lane & 15;
  const long row0 = (long)by * 128;
  const long col0 = (long)bx * 128;

  f32x4 acc[4][4];
#pragma unroll
  for (int i = 0; i < 4; ++i)
#pragma unroll
    for (int j = 0; j < 4; ++j) acc[i][j] = (f32x4){0.f, 0.f, 0.f, 0.f};

  const int sr = tid >> 2;
  const int scc = tid & 3;
  const int qg = (scc - (sr >> 1)) & 3;
  const bf16_t* ap = A + (row0 + sr) * (long)K + qg * 8;
  const bf16_t* bp = B + (col0 + sr) * (long)K + qg * 8;
  unsigned short* la = As + tid * 8;
  unsigned short* lb = Bs + tid * 8;
  const int cc = (quad + ((tm >> 1) & 3)) & 3;

  for (int kt = 0; kt < K; kt += 32) {
    __syncthreads();
    g2l16(ap + kt,           la);
    g2l16(ap + 64l * K + kt, la + 2048);
    g2l16(bp + kt,           lb);
    g2l16(bp + 64l * K + kt, lb + 2048);
    __syncthreads();

    b16x8 af[4], bfr[4];
#pragma unroll
    for (int i = 0; i < 4; ++i)
      af[i] = *(const b16x8*)&As[(wm * 64 + i * 16 + tm) * 32 + cc * 8];
#pragma unroll
    for (int j = 0; j < 4; ++j)
      bfr[j] = *(const b16x8*)&Bs[(wn * 64 + j * 16 + tm) * 32 + cc * 8];
#pragma unroll
    for (int i = 0; i < 4; ++i)
#pragma unroll
      for (int j = 0; j < 4; ++j)
        acc[i][j] = __builtin_amdgcn_mfma_f32_16x16x32_bf16(af[i], bfr[j], acc[i][j], 0, 0, 0);
  }

  if (z != 1) {
#pragma unroll
    for (int i = 0; i < 4; ++i)
#pragma unroll
      for (int j = 0; j < 4; ++j)
#pragma unroll
        for (int r = 0; r < 4; ++r) {
          long row = row0 + wm * 64 + i * 16 + quad * 4 + r;
          long col = col0 + wn * 64 + j * 16 + tm;
          C[row * N + col] = f2b(acc[i][j][r]);
        }
  } else {
    const int fm = wire_flag(xraw, tid);
    const int h = bx * 2 + wn;
    float wgv, bgv, wlv, blv;
    if (fm) {
      wgv = ((const float*)Wg)[h]; bgv = ((const float*)bg)[h];
      wlv = ((const float*)Wl)[h]; blv = ((const float*)bl)[h];
    } else {
      wgv = b2f(((const unsigned short*)Wg)[h]); bgv = b2f(((const unsigned short*)bg)[h]);
      wlv = b2f(((const unsigned short*)Wl)[h]); blv = b2f(((const unsigned short*)bl)[h]);
    }
#pragma unroll
    for (int i = 0; i < 4; ++i)
#pragma unroll
      for (int r = 0; r < 4; ++r) {
        float ss = 0.f, sv = 0.f;
#pragma unroll
        for (int j = 0; j < 4; ++j) {
          const float v = acc[i][j][r];
          ss += v * v; sv += v;
        }
#pragma unroll
        for (int m = 1; m < 16; m <<= 1) {
          ss += __shfl_xor(ss, m);
          sv += __shfl_xor(sv, m);
        }
        const float inv = 1.f / fmaxf(sqrtf(ss), 1e-12f);
        const long row = row0 + wm * 64 + i * 16 + quad * 4 + r;
#pragma unroll
        for (int j = 0; j < 4; ++j)
          C[row * N + col0 + wn * 64 + j * 16 + tm] = f2b(acc[i][j][r] * inv);
        if (tm == 0) {
          const float kbar = sv * inv * (1.f / 64.f);
          const float gm = 1.f / (1.f + expf(-(wgv * kbar + bgv)));
          const float lm = 1.f / (1.f + expf(-(wlv * kbar + blv)));
          const int b = (int)(row >> 10), t = (int)(row & 1023);
          rho[(size_t)(b * 16 + h) * 1024 + t] = (1.f - lm) * gm;
        }
      }
  }
}

// ---------------------------------------------------------------------------
// Output GEMM: 64x64 tile, BK=64, XCD patch decode (xcd owns 16x8 patch).
// ---------------------------------------------------------------------------
__global__ __launch_bounds__(256)
void gemm_out64(const unsigned* __restrict__ xraw,
                const bf16_t* __restrict__ A, const bf16_t* __restrict__ B,
                void* __restrict__ C)
{
  constexpr int K = 1024, N = 1024;
  const int flat = blockIdx.x;
  const int xcd = flat & 7, sl = flat >> 3;        // sl in [0,128)
  const int bx = sl & 15;
  const int by = (xcd << 3) | (sl >> 4);
  __shared__ __align__(16) unsigned short As[64 * 64];
  __shared__ __align__(16) unsigned short Bs[64 * 64];
  const int tid  = threadIdx.x;
  const int lane = tid & 63;
  const int wave = tid >> 6;
  const int quad = lane >> 4, tm = lane & 15;
  const long row0 = (long)by * 64;
  const long col0 = (long)bx * 64;

  f32x4 acc[4];
#pragma unroll
  for (int i = 0; i < 4; ++i) acc[i] = (f32x4){0.f, 0.f, 0.f, 0.f};

  const int sr = tid >> 2;
  const int scc = tid & 3;
  const int qg = (scc - (sr >> 1)) & 3;
  const bf16_t* ap = A + (row0 + sr) * (long)K + qg * 8;
  const bf16_t* bp = B + (col0 + sr) * (long)K + qg * 8;
  unsigned short* la = As + tid * 8;
  unsigned short* lb = Bs + tid * 8;
  const int cc = (quad + ((tm >> 1) & 3)) & 3;

  for (int kt = 0; kt < K; kt += 64) {
    __syncthreads();
    g2l16(ap + kt,      la);
    g2l16(ap + kt + 32, la + 2048);
    g2l16(bp + kt,      lb);
    g2l16(bp + kt + 32, lb + 2048);
    __syncthreads();

    b16x8 bf0 = *(const b16x8*)&Bs[(wave * 16 + tm) * 32 + cc * 8];
    b16x8 bf1 = *(const b16x8*)&Bs[2048 + (wave * 16 + tm) * 32 + cc * 8];
#pragma unroll
    for (int i = 0; i < 4; ++i) {
      b16x8 a0 = *(const b16x8*)&As[(i * 16 + tm) * 32 + cc * 8];
      b16x8 a1 = *(const b16x8*)&As[2048 + (i * 16 + tm) * 32 + cc * 8];
      acc[i] = __builtin_amdgcn_mfma_f32_16x16x32_bf16(a0, bf0, acc[i], 0, 0, 0);
      acc[i] = __builtin_amdgcn_mfma_f32_16x16x32_bf16(a1, bf1, acc[i], 0, 0, 0);
    }
  }

  const int fm = wire_flag(xraw, tid);
#pragma unroll
  for (int i = 0; i < 4; ++i)
#pragma unroll
    for (int r = 0; r < 4; ++r) {
      const long row = row0 + i * 16 + quad * 4 + r;
      const long col = col0 + wave * 16 + tm;
      const float v = acc[i][r];
      if (fm) ((float*)C)[row * N + col] = v;
      else    ((unsigned short*)C)[row * N + col] = f2b(v);
    }
}

// ---------------------------------------------------------------------------
// XOR-swizzled chunk staging: LDS slot (row, c2) holds global chunk c2^(row&7).
// Makes all b128 fragment reads effectively conflict-free (2-way max).
// ---------------------------------------------------------------------------
__device__ __forceinline__ void stage_chunk_x(const unsigned short* G, int n0c, int h,
                                              unsigned short* lds, int tid) {
#pragma unroll
  for (int sh = 0; sh < 2; ++sh) {
    const int idx = sh * 256 + tid;
    const int row = idx >> 3, c2 = idx & 7;
    const int gc = c2 ^ (row & 7);
    g2l16(G + (size_t)(n0c + row) * 1024 + h * 64 + gc * 8, lds + idx * 8);
  }
}
// same for a contiguous 64x64 block (rows of 64 u16)
__device__ __forceinline__ void stage_blk_x(const unsigned short* G,
                                            unsigned short* lds, int tid) {
#pragma unroll
  for (int sh = 0; sh < 2; ++sh) {
    const int idx = sh * 256 + tid;
    const int row = idx >> 3, c2 = idx & 7;
    const int gc = c2 ^ (row & 7);
    g2l16(G + row * 64 + gc * 8, lds + idx * 8);
  }
}
// logical b16x8 read from XOR-staged [64][64]; k0 multiple of 8
__device__ __forceinline__ b16x8 rdx(const unsigned short* lds, int row, int k0) {
  return *(const b16x8*)&lds[row * 64 + (((k0 >> 3) ^ (row & 7)) << 3)];
}
__device__ __forceinline__ float rdx1(const unsigned short* lds, int row, int col) {
  return b2f(lds[row * 64 + (((col >> 3) ^ (row & 7)) << 3) + (col & 7)]);
}

// Build dst[col][row] (stride 72, bf16) from XOR-staged src[row][col],
// optionally scaling row s by sc[s]. Conflict-free reads & vector writes.
__device__ __forceinline__ void transpose_x(const unsigned short* src,
                                            unsigned short* dst,
                                            const float* sc, int tid) {
  const int kc = tid & 63;
  const int s4 = (tid >> 6) * 16;
  u16x8 o0, o1;
#pragma unroll
  for (int i = 0; i < 16; ++i) {
    const int s = s4 + i;
    float v = rdx1(src, s, kc);
    if (sc) v *= sc[s];
    const unsigned short b = f2b(v);
    if (i < 8) o0[i] = b; else o1[i - 8] = b;
  }
  *(u16x8*)&dst[kc * 72 + s4]     = o0;
  *(u16x8*)&dst[kc * 72 + s4 + 8] = o1;
}

// Wave-0 prefix product: aw=a_t, cw=(1-rho)/a, sc=A_c*(1-rho)/a.
__device__ __forceinline__ void rho_scan(const float* rho_s, float* aw, float* cw,
                                         float* sc, int tid) {
  if (tid < 64) {
    const float r = rho_s[tid];
    float p = r;
#pragma unroll
    for (int d = 1; d < 64; d <<= 1) {
      float o = __shfl_up(p, d);
      if (tid >= d) p *= o;
    }
    aw[tid] = p;
    const float c = (1.f - r) / p;
    cw[tid] = c;
    const float Ac = __shfl(p, 63);
    sc[tid] = Ac * c;
  }
}

// ---------------------------------------------------------------------------
// Pass 1: U^T[kc][v] = sum_s sc[s]*k_s[kc]*v_s[v], via D = Ktilde^T * V with
// both operands LDS-transposed (stride 72). Output bf16, coalesced.
// ---------------------------------------------------------------------------
__global__ __launch_bounds__(256)
void chunk_outer(const unsigned short* __restrict__ Kb, const unsigned short* __restrict__ Vb,
                 const float* __restrict__ rho, unsigned short* __restrict__ Ug,
                 float* __restrict__ A_g)
{
  __shared__ __align__(16) unsigned short ks[4096];
  __shared__ __align__(16) unsigned short vs[4096];
  __shared__ __align__(16) unsigned short kt[64 * 72];
  __shared__ __align__(16) unsigned short vt[64 * 72];
  __shared__ float rho_s[64], aw[64], cw[64], sc[64];
  const int tid = threadIdx.x;
  const int bid = blockIdx.x;
  const int bh = bid >> 4, c = bid & 15;
  const int b = bh >> 4, h = bh & 15;
  const int n0c = b * 1024 + c * 64;
  const int lane = tid & 63, wave = tid >> 6;
  const int quad = lane >> 4, tm = lane & 15;

  stage_chunk_x(Kb, n0c, h, ks, tid);
  stage_chunk_x(Vb, n0c, h, vs, tid);
  if (tid < 64) g2l4(rho + (size_t)bh * 1024 + c * 64 + tid, rho_s + tid);
  __syncthreads();
  rho_scan(rho_s, aw, cw, sc, tid);
  __syncthreads();
  transpose_x(ks, kt, sc, tid);     // Ktilde^T (scaled)
  transpose_x(vs, vt, nullptr, tid); // V^T
  __syncthreads();

  // D[m=kc][n=v]: wave owns kc-rows [16w,16w+16)
  const int mrow = 16 * wave + tm;
  b16x8 a0 = *(const b16x8*)&kt[mrow * 72 + quad * 8];
  b16x8 a1 = *(const b16x8*)&kt[mrow * 72 + 32 + quad * 8];
#pragma unroll
  for (int j4 = 0; j4 < 4; ++j4) {
    const int nrow = 16 * j4 + tm;
    b16x8 b0 = *(const b16x8*)&vt[nrow * 72 + quad * 8];
    b16x8 b1 = *(const b16x8*)&vt[nrow * 72 + 32 + quad * 8];
    f32x4 acc = (f32x4){0.f, 0.f, 0.f, 0.f};
    acc = __builtin_amdgcn_mfma_f32_16x16x32_bf16(a0, b0, acc, 0, 0, 0);
    acc = __builtin_amdgcn_mfma_f32_16x16x32_bf16(a1, b1, acc, 0, 0, 0);
#pragma unroll
    for (int r = 0; r < 4; ++r) {
      const int kc = 16 * wave + quad * 4 + r;
      Ug[(size_t)bid * 4096 + kc * 64 + 16 * j4 + tm] = f2b(acc[r]);
    }
  }
  if (tid == 0) A_g[bid] = aw[63];
}

// ---------------------------------------------------------------------------
// Pass 2: elementwise chunk scan in transposed layout. Thread owns 1 element,
// scans 16 chunks; snapshots the pre-update state. 1024 blocks.
// ---------------------------------------------------------------------------
__global__ __launch_bounds__(256)
void chunk_scan(const unsigned short* __restrict__ Ug, const float* __restrict__ A_g,
                unsigned short* __restrict__ Sp)
{
  const int bh = blockIdx.x >> 4;
  const int e  = (blockIdx.x & 15) * 256 + threadIdx.x;
  const size_t base = (size_t)bh * 16 * 4096 + e;
  float S = 0.f;
#pragma unroll
  for (int c = 0; c < 16; ++c) {
    Sp[base + (size_t)c * 4096] = f2b(S);
    S = A_g[bh * 16 + c] * S + b2f(Ug[base + (size_t)c * 4096]);
  }
}

// ---------------------------------------------------------------------------
// Pass 3: P = Q V^T (masked), Y = Pw*K + diag(a_t) Q S_prev.
// K fed as B-operand via LDS transpose; S_prev arrives pre-transposed.
// ---------------------------------------------------------------------------
__global__ __launch_bounds__(256)
void chunk_y(const unsigned short* __restrict__ Qb, const unsigned short* __restrict__ Kb,
             const unsigned short* __restrict__ Vb, const unsigned short* __restrict__ Sp,
             const float* __restrict__ rho, unsigned short* __restrict__ Yb)
{
  __shared__ __align__(16) unsigned short qs[4096];
  __shared__ __align__(16) unsigned short ks[4096];
  __shared__ __align__(16) unsigned short vs[4096];
  __shared__ __align__(16) unsigned short ss[4096];   // S^T, XOR-staged
  __shared__ __align__(16) unsigned short kt[64 * 72]; // K^T
  __shared__ __align__(16) unsigned short pt[64 * 72]; // Pw
  __shared__ float rho_s[64], aw[64], cw[64], sc[64];
  const int tid = threadIdx.x;
  const int bid = blockIdx.x;
  const int bh = bid >> 4, c = bid & 15;
  const int b = bh >> 4, h = bh & 15;
  const int n0c = b * 1024 + c * 64;
  const int lane = tid & 63, wave = tid >> 6;
  const int quad = lane >> 4, tm = lane & 15;

  stage_chunk_x(Qb, n0c, h, qs, tid);
  stage_chunk_x(Kb, n0c, h, ks, tid);
  stage_chunk_x(Vb, n0c, h, vs, tid);
  stage_blk_x(Sp + (size_t)bid * 4096, ss, tid);
  if (tid < 64) g2l4(rho + (size_t)bh * 1024 + c * 64 + tid, rho_s + tid);
  __syncthreads();
  rho_scan(rho_s, aw, cw, sc, tid);
  __syncthreads();
  transpose_x(ks, kt, nullptr, tid);   // K^T for phase B (barrier below)

  __bf16* ptb = (__bf16*)pt;
  const int trow = 16 * wave + tm;

  // Phase A: P tiles + mask -> pt (wave-private rows, stride 72)
  b16x8 af_q[2];
#pragma unroll
  for (int kk = 0; kk < 2; ++kk)
    af_q[kk] = rdx(qs, trow, kk * 32 + quad * 8);
#pragma unroll
  for (int j4 = 0; j4 < 4; ++j4) {
    f32x4 acc = (f32x4){0.f, 0.f, 0.f, 0.f};
#pragma unroll
    for (int kk = 0; kk < 2; ++kk) {
      const b16x8 bf = rdx(vs, 16 * j4 + tm, kk * 32 + quad * 8);
      acc = __builtin_amdgcn_mfma_f32_16x16x32_bf16(af_q[kk], bf, acc, 0, 0, 0);
    }
    const int s = 16 * j4 + tm;
    const float cws = cw[s];
#pragma unroll
    for (int r = 0; r < 4; ++r) {
      const int t = 16 * wave + quad * 4 + r;
      const float w = (s <= t) ? aw[t] * cws : 0.f;
      ptb[t * 72 + s] = (__bf16)(acc[r] * w);
    }
  }

  // Scaled Q fragment (a_t * q_t) + P fragments
  const float at = aw[trow];
  b16x8 af_qs[2], af_p[2];
#pragma unroll
  for (int kk = 0; kk < 2; ++kk) {
    b16x8 t8;
#pragma unroll
    for (int j = 0; j < 8; ++j) t8[j] = (__bf16)(at * (float)af_q[kk][j]);
    af_qs[kk] = t8;
    af_p[kk] = *(const b16x8*)&pt[trow * 72 + kk * 32 + quad * 8];
  }
  __syncthreads();   // kt complete (pt rows are wave-private)

  // Phase B: Y[t][kc] = sum_s Pw[t][s] K[s][kc] + sum_v a_t q[t][v] S[v][kc]
#pragma unroll
  for (int j4 = 0; j4 < 4; ++j4) {
    const int kc = 16 * j4 + tm;
    f32x4 acc = (f32x4){0.f, 0.f, 0.f, 0.f};
#pragma unroll
    for (int kk = 0; kk < 2; ++kk) {
      const int kbase = kk * 32 + quad * 8;
      const b16x8 bk = *(const b16x8*)&kt[kc * 72 + kbase];
      const b16x8 bs = rdx(ss, kc, kbase);
      acc = __builtin_amdgcn_mfma_f32_16x16x32_bf16(af_p[kk],  bk, acc, 0, 0, 0);
      acc = __builtin_amdgcn_mfma_f32_16x16x32_bf16(af_qs[kk], bs, acc, 0, 0, 0);
    }
#pragma unroll
    for (int r = 0; r < 4; ++r) {
      const int t = 16 * wave + quad * 4 + r;
      Yb[(size_t)(n0c + t) * 1024 + h * 64 + kc] = f2b(acc[r]);
    }
  }
}

// ---------------------------------------------------------------------------
extern "C" void kernel_launch(void* const* d_in, const int* in_sizes, int n_in,
                              void* d_out, int out_size, void* d_ws, size_t ws_size,
                              hipStream_t stream) {
  const void* x  = d_in[0];
  const void* Wq = d_in[1];
  const void* Wk = d_in[2];
  const void* Wv = d_in[3];
  const void* Wo = d_in[4];

  char* ws = (char*)d_ws;
  const size_t MB = 1ull << 20;
  unsigned short* x_b  = (unsigned short*)(ws);
  unsigned short* Wq_b = (unsigned short*)(ws + 8 * MB);
  unsigned short* Wk_b = (unsigned short*)(ws + 10 * MB);
  unsigned short* Wv_b = (unsigned short*)(ws + 12 * MB);
  unsigned short* Wo_b = (unsigned short*)(ws + 14 * MB);
  unsigned short* Qb = (unsigned short*)(ws + 16 * MB);
  unsigned short* Kb = (unsigned short*)(ws + 24 * MB);
  unsigned short* Vb = (unsigned short*)(ws + 32 * MB);
  unsigned short* Yb = (unsigned short*)(ws + 40 * MB);
  unsigned short* Ug = (unsigned short*)(ws + 48 * MB);
  unsigned short* Sp = (unsigned short*)(ws + 64 * MB);
  float*  rh   = (float*)(ws + 72 * MB);
  float*  A_g  = (float*)(ws + 72 * MB + 256 * 1024);

  dim3 blk(256);
  convert_all<<<dim3(4096), blk, 0, stream>>>(x, Wq, Wk, Wv, Wo,
                                              x_b, Wq_b, Wk_b, Wv_b, Wo_b);
  gemm_qkv<<<dim3(768), blk, 0, stream>>>((const unsigned*)x,
      (const bf16_t*)x_b, (const bf16_t*)Wq_b, (const bf16_t*)Wk_b, (const bf16_t*)Wv_b,
      Qb, Kb, Vb, d_in[5], d_in[6], d_in[7], d_in[8], rh);
  chunk_outer<<<dim3(1024), blk, 0, stream>>>(Kb, Vb, rh, Ug, A_g);
  chunk_scan<<<dim3(1024), blk, 0, stream>>>(Ug, A_g, Sp);
  chunk_y<<<dim3(1024), blk, 0, stream>>>(Qb, Kb, Vb, Sp, rh, Yb);
  gemm_out64<<<dim3(1024), blk, 0, stream>>>((const unsigned*)x,
      (const bf16_t*)Yb, (const bf16_t*)Wo_b, d_out);
}